// Round 9
// baseline (106.785 us; speedup 1.0000x reference)
//
#include <hip/hip_runtime.h>
#include <hip/hip_bf16.h>

typedef __hip_bfloat16 bf16;
typedef float in_t;
typedef float out_t;
typedef __attribute__((ext_vector_type(8))) short short8;   // 8 bf16 MFMA operand
typedef __attribute__((ext_vector_type(4))) float f32x4;    // MFMA accumulator

#define CH    64
#define CIN1  32
#define CIN2  64
#define S1    186624   // 36*72*72
#define W1    5184     // 72*72
#define S2    23328    // 18*36*36
#define W2    1296     // 36*36
#define LDSTR 1297     // k_M LDS row stride (coprime with 32)
#define BSTR  104      // k_corr patch lds bf16 row stride
#define XSTR  134      // k_proj_x LDS fp32 row stride
#define HWSTR 76       // k_pool_hw LDS row stride (float4-aligned)
#define INV_NZ (1.0f/(288.0f + 1e-5f))

static __device__ __forceinline__ unsigned short f2bu(float f) {
    bf16 h = __float2bfloat16(f);
    unsigned short u;
    __builtin_memcpy(&u, &h, 2);
    return u;
}

// ---- proj_x as MFMA GEMM: xq(64,S1) = W(64,32) x x(32,S1) + b, bf16 out
__global__ __launch_bounds__(256) void k_proj_x(
    const in_t* __restrict__ x, const in_t* __restrict__ w, const in_t* __restrict__ bias,
    bf16* __restrict__ xq)
{
    __shared__ float          xl[CIN1*XSTR];     // 17152 B
    __shared__ unsigned short wl[CH*CIN1];       //  4096 B
    int t   = threadIdx.x;
    int gs0 = blockIdx.x*128;

    #pragma unroll
    for (int i = 0; i < 4; ++i) {
        int fi = t + i*256;
        int c  = fi >> 5, s4 = fi & 31;
        float4 v = *reinterpret_cast<const float4*>(&x[(size_t)c*S1 + gs0 + s4*4]);
        float* dst = &xl[c*XSTR + s4*4];
        *reinterpret_cast<float2*>(dst)     = (float2){v.x, v.y};
        *reinterpret_cast<float2*>(dst + 2) = (float2){v.z, v.w};
    }
    #pragma unroll
    for (int i = 0; i < 2; ++i) {
        int wi = t + i*256;
        int o  = wi >> 3, c4 = wi & 7;
        float4 v = *reinterpret_cast<const float4*>(&w[o*CIN1 + c4*4]);
        ushort4 u = { f2bu(v.x), f2bu(v.y), f2bu(v.z), f2bu(v.w) };
        *reinterpret_cast<ushort4*>(&wl[o*CIN1 + c4*4]) = u;
    }
    int l    = t & 63, wv = t >> 6;
    int lcol = l & 15, loct = l >> 4;
    float bly[4];
    #pragma unroll
    for (int og = 0; og < 4; ++og) bly[og] = bias[og*16 + lcol];
    __syncthreads();

    short8 wf[4];
    #pragma unroll
    for (int og = 0; og < 4; ++og)
        wf[og] = *reinterpret_cast<const short8*>(&wl[(og*16 + lcol)*CIN1 + loct*8]);

    #pragma unroll
    for (int mt = 0; mt < 2; ++mt) {
        int s_base = (wv*2 + mt)*16;
        union { short8 v; unsigned short u[8]; } af;
        #pragma unroll
        for (int j = 0; j < 8; ++j)
            af.u[j] = f2bu(xl[(loct*8 + j)*XSTR + s_base + lcol]);
        #pragma unroll
        for (int og = 0; og < 4; ++og) {
            f32x4 d = { bly[og], bly[og], bly[og], bly[og] };
            d = __builtin_amdgcn_mfma_f32_16x16x32_bf16(af.v, wf[og], d, 0, 0, 0);
            ushort4 r = { f2bu(d[0]), f2bu(d[1]), f2bu(d[2]), f2bu(d[3]) };
            int o = og*16 + lcol;
            *reinterpret_cast<ushort4*>(
                (unsigned short*)xq + (size_t)o*S1 + gs0 + s_base + loct*4) = r;
        }
    }
}

// ---- yk: 512 blocks = 32 o-pairs x 16 spatial chunks of 1458
__global__ __launch_bounds__(256) void k_proj_y(
    const in_t* __restrict__ y, const in_t* __restrict__ w, const in_t* __restrict__ bias,
    float* __restrict__ yk)
{
    int bid   = blockIdx.x;
    int o0    = (bid >> 4) * 2;
    int chunk = bid & 15;
    int t = threadIdx.x;
    float b0 = bias[o0], b1 = bias[o0+1];
    for (int it = 0; it < 6; ++it) {
        int sl = it*256 + t;
        if (sl >= 1458) break;
        int s = chunk*1458 + sl;
        float a0 = b0, a1 = b1;
        #pragma unroll
        for (int cc = 0; cc < CIN2; ++cc) {
            float yv = y[cc*S2 + s];
            a0 += w[o0*CIN2 + cc]     * yv;
            a1 += w[(o0+1)*CIN2 + cc] * yv;
        }
        yk[o0*S2 + s]     = a0;
        yk[(o0+1)*S2 + s] = a1;
    }
}

// ---- pool stage 1: per-plane 3x3 hw-avg (count_include_pad=False is separable)
// grid = 64ch * 36d = 2304 blocks; coalesced plane load -> LDS -> 9-tap pool
__global__ __launch_bounds__(256) void k_pool_hw(const in_t* __restrict__ z,
                                                 float* __restrict__ hw)
{
    __shared__ float raw[72*HWSTR];               // 21888 B
    int bid = blockIdx.x;
    int c = bid / 36, d = bid - (bid/36)*36;
    int t = threadIdx.x;
    const float4* zp = reinterpret_cast<const float4*>(z + ((size_t)c*36 + d)*W1);
    for (int i = t; i < 1296; i += 256) {         // fully coalesced float4 stream
        float4 v = zp[i];
        int r = i / 18, q = i - (i/18)*18;
        *reinterpret_cast<float4*>(&raw[r*HWSTR + q*4]) = v;
    }
    __syncthreads();
    float* hwp = hw + ((size_t)c*36 + d)*W2;
    for (int idx = t; idx < 1296; idx += 256) {
        int oh = idx / 36, ow = idx - (idx/36)*36;
        int h0 = oh ? 2*oh-1 : 0, h1 = 2*oh+1;    // h1 <= 71
        int w0 = ow ? 2*ow-1 : 0, w1 = 2*ow+1;
        float s = 0.f;
        for (int h = h0; h <= h1; ++h)
            for (int w = w0; w <= w1; ++w)
                s += raw[h*HWSTR + w];
        int cnt = (h1-h0+1)*(w1-w0+1);            // 4, 6, or 9
        float inv = (cnt == 9) ? (1.f/9.f) : ((cnt == 6) ? (1.f/6.f) : 0.25f);
        hwp[idx] = s * inv;
    }
}

// ---- pool stage 2: 3-tap d-avg: hw(64,36,1296) -> xd(64,18,1296)
__global__ __launch_bounds__(256) void k_pool_d(const float* __restrict__ hw,
                                                float* __restrict__ xd)
{
    int idx = blockIdx.x*256 + threadIdx.x;       // 1492992 = 5832*256 exact
    int c = idx / (18*W2);
    int r = idx - c*(18*W2);
    int od = r / W2, hwi = r - od*W2;
    const float* p = hw + ((size_t)c*36)*W2 + hwi;
    int d0 = od ? 2*od-1 : 0, d1 = 2*od+1;        // d1 <= 35
    float s = 0.f;
    for (int d = d0; d <= d1; ++d) s += p[(size_t)d*W2];
    xd[idx] = s * ((d1 - d0) == 1 ? 0.5f : (1.f/3.f));
}

// ---- M[c,k1,k2] = sum_m Uxd[c,k1,m]*Uy[c,k2,m]; output bf16 zero-padded [c][96][96]
__global__ __launch_bounds__(256) void k_M(
    const float* __restrict__ xd, const float* __restrict__ yk, unsigned short* __restrict__ Mg)
{
    __shared__ float xl[3*LDSTR];
    __shared__ float yl[3*LDSTR];
    int b = blockIdx.x;
    int c = b / 9, r = b - c*9;
    int g = r / 3, h = r - g*3;
    int t = threadIdx.x;
    int t1 = t / 27, t2 = t - (t/27)*27;
    int offx[3];
    #pragma unroll
    for (int a = 0; a < 3; ++a) {
        int kl = t1*3 + a;
        offx[a] = (kl/9)*LDSTR + (kl - (kl/9)*9);
    }
    int offy = (t2/9)*LDSTR + (t2 - (t2/9)*9);
    float acc[3] = {};
    for (int ph2 = 0; ph2 < 2; ++ph2) {
        __syncthreads();
        for (int idx = t; idx < 3*W2; idx += 256) {
            int rr = idx / W2, col = idx - rr*W2;
            xl[rr*LDSTR + col] = xd[c*S2 + (ph2*9 + g*3 + rr)*W2 + col];
            yl[rr*LDSTR + col] = yk[c*S2 + (ph2*9 + h*3 + rr)*W2 + col];
        }
        __syncthreads();
        if (t < 243) {
            for (int m = 0; m < 144; ++m) {
                int cb = m*9;
                float yv = yl[cb + offy];
                #pragma unroll
                for (int a = 0; a < 3; ++a)
                    acc[a] += xl[cb + offx[a]] * yv;
            }
        }
    }
    if (t < 243) {
        #pragma unroll
        for (int a = 0; a < 3; ++a) {
            int k1 = g*27 + t1*3 + a;
            Mg[c*9216 + k1*96 + (h*27 + t2)] = f2bu(acc[a]);
        }
    }
    if (r == 0) {
        for (int idx = t; idx < 2655; idx += 256) {
            int row, col;
            if (idx < 1440) { int q = idx/96; row = 81 + q; col = idx - q*96; }
            else { int j = idx - 1440; int q = j/15; row = q; col = 81 + (j - q*15); }
            Mg[c*9216 + row*96 + col] = 0;
        }
    }
}

// ---- MFMA corr: per (channel, 192-patch chunk): C(96x192) = Mg(96x96,bf16) x Uxq^T
__global__ __launch_bounds__(256, 3) void k_corr(
    const unsigned short* __restrict__ Mg, const bf16* __restrict__ xq,
    const in_t* __restrict__ z, out_t* __restrict__ out)
{
    __shared__ __align__(16) unsigned short Pl[192*BSTR];   // 39936 B
    int bid = blockIdx.x;
    int c   = bid / 12;
    int rem = bid - c*12;
    int ph  = rem / 3;
    int ck  = rem - ph*3;
    int colbase = ck*1728;
    int t = threadIdx.x;

    for (int idx = t; idx < 192*15; idx += 256) {
        int r = idx/15;
        Pl[r*BSTR + 81 + (idx - r*15)] = 0;
    }
    const unsigned short* xqu =
        (const unsigned short*)(xq + (size_t)c*S1 + (size_t)(ph*9)*W1 + colbase);
    for (int idx = t; idx < 3888; idx += 256) {
        int i2 = idx / 432, v4 = idx - i2*432;
        ushort4 vv = *reinterpret_cast<const ushort4*>(xqu + (size_t)i2*W1 + v4*4);
        int col = v4*4;
        unsigned short uu[4] = {vv.x, vv.y, vv.z, vv.w};
        #pragma unroll
        for (int j = 0; j < 4; ++j) {
            int cc = col + j;
            int p = cc/9, j2 = cc - p*9;
            Pl[p*BSTR + i2*9 + j2] = uu[j];
        }
    }
    __syncthreads();

    int wv = t >> 6, l = t & 63;
    int lrow = l & 15, lhi = l >> 4;

    short8 bfr[3][3];
    #pragma unroll
    for (int ntl = 0; ntl < 3; ++ntl) {
        int n = (wv*3 + ntl)*16 + lrow;
        #pragma unroll
        for (int kk = 0; kk < 3; ++kk)
            bfr[ntl][kk] = *reinterpret_cast<const short8*>(&Pl[n*BSTR + kk*32 + lhi*8]);
    }

    f32x4 acc[6][3];
    #pragma unroll
    for (int mt = 0; mt < 6; ++mt)
        #pragma unroll
        for (int ntl = 0; ntl < 3; ++ntl)
            acc[mt][ntl] = (f32x4){0.f,0.f,0.f,0.f};

    const unsigned short* Mc = Mg + c*9216;
    #pragma unroll
    for (int mt = 0; mt < 6; ++mt) {
        short8 afr[3];
        #pragma unroll
        for (int kk = 0; kk < 3; ++kk)
            afr[kk] = *reinterpret_cast<const short8*>(Mc + (mt*16 + lrow)*96 + kk*32 + lhi*8);
        #pragma unroll
        for (int ntl = 0; ntl < 3; ++ntl) {
            f32x4 d = acc[mt][ntl];
            #pragma unroll
            for (int kk = 0; kk < 3; ++kk)
                d = __builtin_amdgcn_mfma_f32_16x16x32_bf16(afr[kk], bfr[ntl][kk], d, 0, 0, 0);
            acc[mt][ntl] = d;
        }
    }
    __syncthreads();

    float* stage = reinterpret_cast<float*>(Pl);
    #pragma unroll
    for (int pass = 0; pass < 2; ++pass) {
        if ((wv >> 1) == pass) {
            #pragma unroll
            for (int mt = 0; mt < 6; ++mt)
                #pragma unroll
                for (int ntl = 0; ntl < 3; ++ntl) {
                    int n = (wv*3 + ntl)*16 + lrow - pass*96;
                    #pragma unroll
                    for (int r = 0; r < 4; ++r) {
                        int m = mt*16 + lhi*4 + r;
                        if (m <= 80) {
                            int i = m/9, j = m - 9*i;
                            stage[i*864 + n*9 + j] = acc[mt][ntl][r];
                        }
                    }
                }
        }
        __syncthreads();
        for (int idx = t; idx < 1944; idx += 256) {
            int i = idx/216, c4 = idx - i*216;
            float4 sv = *reinterpret_cast<const float4*>(&stage[i*864 + c4*4]);
            int ga = c*S1 + (ph*9 + i)*W1 + colbase + pass*864 + c4*4;
            float4 dv = *reinterpret_cast<const float4*>(&z[ga]);
            float4 ov;
            float cr;
            cr = sv.x*INV_NZ; ov.x = dv.x + (cr > 0.f ? cr : 0.2f*cr)*dv.x;
            cr = sv.y*INV_NZ; ov.y = dv.y + (cr > 0.f ? cr : 0.2f*cr)*dv.y;
            cr = sv.z*INV_NZ; ov.z = dv.z + (cr > 0.f ? cr : 0.2f*cr)*dv.z;
            cr = sv.w*INV_NZ; ov.w = dv.w + (cr > 0.f ? cr : 0.2f*cr)*dv.w;
            *reinterpret_cast<float4*>(&out[ga]) = ov;
        }
        __syncthreads();
    }
}

extern "C" void kernel_launch(void* const* d_in, const int* in_sizes, int n_in,
                              void* d_out, int out_size, void* d_ws, size_t ws_size,
                              hipStream_t stream)
{
    (void)in_sizes; (void)n_in; (void)out_size; (void)ws_size;
    const in_t* x     = (const in_t*)d_in[0];
    const in_t* y     = (const in_t*)d_in[1];
    const in_t* z     = (const in_t*)d_in[2];
    const in_t* w_img = (const in_t*)d_in[3];
    const in_t* b_img = (const in_t*)d_in[4];
    const in_t* w_fea = (const in_t*)d_in[5];
    const in_t* b_fea = (const in_t*)d_in[6];
    out_t* out = (out_t*)d_out;

    char* ws = (char*)d_ws;
    bf16*           xq  = (bf16*)          (ws + 0);          // 23,887,872
    float*          yk  = (float*)         (ws + 23887872);   // 5,971,968
    float*          xd  = (float*)         (ws + 29859840);   // 5,971,968
    unsigned short* Mg  = (unsigned short*)(ws + 35831808);   // 1,179,648
    float*          hwb = (float*)         (ws + 37011456);   // 64*36*1296*4 = 11,943,936

    hipLaunchKernelGGL(k_proj_x,  dim3(1458), dim3(256), 0, stream, x, w_img, b_img, xq);
    hipLaunchKernelGGL(k_proj_y,  dim3(512),  dim3(256), 0, stream, y, w_fea, b_fea, yk);
    hipLaunchKernelGGL(k_pool_hw, dim3(2304), dim3(256), 0, stream, z, hwb);
    hipLaunchKernelGGL(k_pool_d,  dim3(5832), dim3(256), 0, stream, hwb, xd);
    hipLaunchKernelGGL(k_M,       dim3(576),  dim3(256), 0, stream, xd, yk, Mg);
    hipLaunchKernelGGL(k_corr,    dim3(768),  dim3(256), 0, stream, Mg, xq, z, out);
}

// Round 10
// 90.593 us; speedup vs baseline: 1.1787x; 1.1787x over previous
//
#include <hip/hip_runtime.h>
#include <hip/hip_bf16.h>

typedef __hip_bfloat16 bf16;
typedef float in_t;
typedef float out_t;
typedef __attribute__((ext_vector_type(8))) short short8;   // 8 bf16 MFMA operand
typedef __attribute__((ext_vector_type(4))) float f32x4;    // MFMA accumulator

#define CH    64
#define CIN1  32
#define CIN2  64
#define S1    186624   // 36*72*72
#define W1    5184     // 72*72
#define S2    23328    // 18*36*36
#define W2    1296     // 36*36
#define LDSTR 1297     // k_M LDS row stride (coprime with 32)
#define BSTR  104      // k_corr patch lds bf16 row stride
#define XSTR  134      // k_proj_x LDS fp32 row stride
#define HWSTR 76       // k_pool LDS row stride (float4-aligned; stride-2 reads = free 2-way)
#define INV_NZ (1.0f/(288.0f + 1e-5f))

static __device__ __forceinline__ unsigned short f2bu(float f) {
    bf16 h = __float2bfloat16(f);
    unsigned short u;
    __builtin_memcpy(&u, &h, 2);
    return u;
}

// ---- proj_x as MFMA GEMM: xq(64,S1) = W(64,32) x x(32,S1) + b, bf16 out
__global__ __launch_bounds__(256) void k_proj_x(
    const in_t* __restrict__ x, const in_t* __restrict__ w, const in_t* __restrict__ bias,
    bf16* __restrict__ xq)
{
    __shared__ float          xl[CIN1*XSTR];     // 17152 B
    __shared__ unsigned short wl[CH*CIN1];       //  4096 B
    int t   = threadIdx.x;
    int gs0 = blockIdx.x*128;

    #pragma unroll
    for (int i = 0; i < 4; ++i) {
        int fi = t + i*256;
        int c  = fi >> 5, s4 = fi & 31;
        float4 v = *reinterpret_cast<const float4*>(&x[(size_t)c*S1 + gs0 + s4*4]);
        float* dst = &xl[c*XSTR + s4*4];
        *reinterpret_cast<float2*>(dst)     = (float2){v.x, v.y};
        *reinterpret_cast<float2*>(dst + 2) = (float2){v.z, v.w};
    }
    #pragma unroll
    for (int i = 0; i < 2; ++i) {
        int wi = t + i*256;
        int o  = wi >> 3, c4 = wi & 7;
        float4 v = *reinterpret_cast<const float4*>(&w[o*CIN1 + c4*4]);
        ushort4 u = { f2bu(v.x), f2bu(v.y), f2bu(v.z), f2bu(v.w) };
        *reinterpret_cast<ushort4*>(&wl[o*CIN1 + c4*4]) = u;
    }
    int l    = t & 63, wv = t >> 6;
    int lcol = l & 15, loct = l >> 4;
    float bly[4];
    #pragma unroll
    for (int og = 0; og < 4; ++og) bly[og] = bias[og*16 + lcol];
    __syncthreads();

    short8 wf[4];
    #pragma unroll
    for (int og = 0; og < 4; ++og)
        wf[og] = *reinterpret_cast<const short8*>(&wl[(og*16 + lcol)*CIN1 + loct*8]);

    #pragma unroll
    for (int mt = 0; mt < 2; ++mt) {
        int s_base = (wv*2 + mt)*16;
        union { short8 v; unsigned short u[8]; } af;
        #pragma unroll
        for (int j = 0; j < 8; ++j)
            af.u[j] = f2bu(xl[(loct*8 + j)*XSTR + s_base + lcol]);
        #pragma unroll
        for (int og = 0; og < 4; ++og) {
            f32x4 d = { bly[og], bly[og], bly[og], bly[og] };
            d = __builtin_amdgcn_mfma_f32_16x16x32_bf16(af.v, wf[og], d, 0, 0, 0);
            ushort4 r = { f2bu(d[0]), f2bu(d[1]), f2bu(d[2]), f2bu(d[3]) };
            int o = og*16 + lcol;
            *reinterpret_cast<ushort4*>(
                (unsigned short*)xq + (size_t)o*S1 + gs0 + s_base + loct*4) = r;
        }
    }
}

// ---- proj_y as 1-wave MFMA blocks: yk(64,S2) = Wf(64,64) x y(64,S2) + b, fp32 out
// grid = S2/16 = 1458 blocks x 64 threads; no LDS, no barrier
__global__ __launch_bounds__(64) void k_proj_y(
    const in_t* __restrict__ y, const in_t* __restrict__ w, const in_t* __restrict__ bias,
    float* __restrict__ yk)
{
    int s0 = blockIdx.x * 16;
    int l  = threadIdx.x;
    int lcol = l & 15, loct = l >> 4;

    // A-fragments: y rows (c = kk*32 + loct*8 + j), col s0+lcol
    union { short8 v; unsigned short u[8]; } af[2];
    #pragma unroll
    for (int kk = 0; kk < 2; ++kk)
        #pragma unroll
        for (int j = 0; j < 8; ++j)
            af[kk].u[j] = f2bu(y[(size_t)(kk*32 + loct*8 + j)*S2 + s0 + lcol]);

    float b = bias[lcol];   // o = og*16 + lcol; bias varies only via lcol per og below
    #pragma unroll
    for (int og = 0; og < 4; ++og) {
        int o = og*16 + lcol;
        // B-fragments from w row o (fp32 -> bf16)
        union { short8 v; unsigned short u[8]; } wf[2];
        #pragma unroll
        for (int kk = 0; kk < 2; ++kk) {
            float4 a = *reinterpret_cast<const float4*>(&w[o*CIN2 + kk*32 + loct*8]);
            float4 bq = *reinterpret_cast<const float4*>(&w[o*CIN2 + kk*32 + loct*8 + 4]);
            wf[kk].u[0]=f2bu(a.x); wf[kk].u[1]=f2bu(a.y); wf[kk].u[2]=f2bu(a.z); wf[kk].u[3]=f2bu(a.w);
            wf[kk].u[4]=f2bu(bq.x); wf[kk].u[5]=f2bu(bq.y); wf[kk].u[6]=f2bu(bq.z); wf[kk].u[7]=f2bu(bq.w);
        }
        float bo = bias[o];
        f32x4 d = { bo, bo, bo, bo };
        d = __builtin_amdgcn_mfma_f32_16x16x32_bf16(af[0].v, wf[0].v, d, 0, 0, 0);
        d = __builtin_amdgcn_mfma_f32_16x16x32_bf16(af[1].v, wf[1].v, d, 0, 0, 0);
        // D: col(n)=lcol -> o, row(m)=loct*4+r -> s
        float4 r = { d[0], d[1], d[2], d[3] };
        *reinterpret_cast<float4*>(&yk[(size_t)o*S2 + s0 + loct*4]) = r;
    }
    (void)b;
}

// ---- fused AvgPool3d k3 s2 p1 (count_include_pad=False): register d-sum + LDS hw-pool
// grid = 64ch * 18od = 1152 blocks; planes contiguous -> 3 coalesced float4 streams
__global__ __launch_bounds__(256) void k_pool(const in_t* __restrict__ z, float* __restrict__ xd)
{
    __shared__ float dsum[72*HWSTR];              // 21888 B
    int bid = blockIdx.x;
    int c = bid / 18, od = bid - (bid/18)*18;
    int t = threadIdx.x;
    int dlo = od ? 2*od - 1 : 0;
    int nd  = od ? 3 : 2;                         // od=17 -> d 33..35, still 3
    const float4* zp = reinterpret_cast<const float4*>(z + ((size_t)c*36 + dlo)*W1);
    if (nd == 3) {
        for (int i = t; i < 1296; i += 256) {
            float4 a = zp[i], b = zp[1296 + i], e = zp[2592 + i];
            float4 s = { a.x+b.x+e.x, a.y+b.y+e.y, a.z+b.z+e.z, a.w+b.w+e.w };
            int r = i / 18, q = i - (i/18)*18;
            *reinterpret_cast<float4*>(&dsum[r*HWSTR + q*4]) = s;
        }
    } else {
        for (int i = t; i < 1296; i += 256) {
            float4 a = zp[i], b = zp[1296 + i];
            float4 s = { a.x+b.x, a.y+b.y, a.z+b.z, a.w+b.w };
            int r = i / 18, q = i - (i/18)*18;
            *reinterpret_cast<float4*>(&dsum[r*HWSTR + q*4]) = s;
        }
    }
    __syncthreads();
    float icd = (nd == 3) ? (1.f/3.f) : 0.5f;
    float* xdp = xd + (size_t)c*S2 + (size_t)od*W2;
    for (int idx = t; idx < 1296; idx += 256) {
        int oh = idx / 36, ow = idx - (idx/36)*36;
        int h0 = oh ? 2*oh-1 : 0, h1 = 2*oh+1;
        int w0 = ow ? 2*ow-1 : 0, w1 = 2*ow+1;
        float s = 0.f;
        for (int h = h0; h <= h1; ++h)
            for (int w = w0; w <= w1; ++w)
                s += dsum[h*HWSTR + w];
        float ich = (h1 - h0) == 1 ? 0.5f : (1.f/3.f);
        float icw = (w1 - w0) == 1 ? 0.5f : (1.f/3.f);
        xdp[idx] = s * icd * ich * icw;
    }
}

// ---- M[c,k1,k2] = sum_m Uxd[c,k1,m]*Uy[c,k2,m]; output bf16 zero-padded [c][96][96]
__global__ __launch_bounds__(256) void k_M(
    const float* __restrict__ xd, const float* __restrict__ yk, unsigned short* __restrict__ Mg)
{
    __shared__ float xl[3*LDSTR];
    __shared__ float yl[3*LDSTR];
    int b = blockIdx.x;
    int c = b / 9, r = b - c*9;
    int g = r / 3, h = r - g*3;
    int t = threadIdx.x;
    int t1 = t / 27, t2 = t - (t/27)*27;
    int offx[3];
    #pragma unroll
    for (int a = 0; a < 3; ++a) {
        int kl = t1*3 + a;
        offx[a] = (kl/9)*LDSTR + (kl - (kl/9)*9);
    }
    int offy = (t2/9)*LDSTR + (t2 - (t2/9)*9);
    float acc[3] = {};
    for (int ph2 = 0; ph2 < 2; ++ph2) {
        __syncthreads();
        for (int idx = t; idx < 3*W2; idx += 256) {
            int rr = idx / W2, col = idx - rr*W2;
            xl[rr*LDSTR + col] = xd[c*S2 + (ph2*9 + g*3 + rr)*W2 + col];
            yl[rr*LDSTR + col] = yk[c*S2 + (ph2*9 + h*3 + rr)*W2 + col];
        }
        __syncthreads();
        if (t < 243) {
            for (int m = 0; m < 144; ++m) {
                int cb = m*9;
                float yv = yl[cb + offy];
                #pragma unroll
                for (int a = 0; a < 3; ++a)
                    acc[a] += xl[cb + offx[a]] * yv;
            }
        }
    }
    if (t < 243) {
        #pragma unroll
        for (int a = 0; a < 3; ++a) {
            int k1 = g*27 + t1*3 + a;
            Mg[c*9216 + k1*96 + (h*27 + t2)] = f2bu(acc[a]);
        }
    }
    if (r == 0) {
        for (int idx = t; idx < 2655; idx += 256) {
            int row, col;
            if (idx < 1440) { int q = idx/96; row = 81 + q; col = idx - q*96; }
            else { int j = idx - 1440; int q = j/15; row = q; col = 81 + (j - q*15); }
            Mg[c*9216 + row*96 + col] = 0;
        }
    }
}

// ---- MFMA corr: per (channel, 192-patch chunk): C(96x192) = Mg(96x96,bf16) x Uxq^T
__global__ __launch_bounds__(256, 4) void k_corr(
    const unsigned short* __restrict__ Mg, const bf16* __restrict__ xq,
    const in_t* __restrict__ z, out_t* __restrict__ out)
{
    __shared__ __align__(16) unsigned short Pl[192*BSTR];   // 39936 B -> 4 blocks/CU
    int bid = blockIdx.x;
    int c   = bid / 12;
    int rem = bid - c*12;
    int ph  = rem / 3;
    int ck  = rem - ph*3;
    int colbase = ck*1728;
    int t = threadIdx.x;

    for (int idx = t; idx < 192*15; idx += 256) {
        int r = idx/15;
        Pl[r*BSTR + 81 + (idx - r*15)] = 0;
    }
    const unsigned short* xqu =
        (const unsigned short*)(xq + (size_t)c*S1 + (size_t)(ph*9)*W1 + colbase);
    for (int idx = t; idx < 3888; idx += 256) {
        int i2 = idx / 432, v4 = idx - i2*432;
        ushort4 vv = *reinterpret_cast<const ushort4*>(xqu + (size_t)i2*W1 + v4*4);
        int col = v4*4;
        unsigned short uu[4] = {vv.x, vv.y, vv.z, vv.w};
        #pragma unroll
        for (int j = 0; j < 4; ++j) {
            int cc = col + j;
            int p = cc/9, j2 = cc - p*9;
            Pl[p*BSTR + i2*9 + j2] = uu[j];
        }
    }
    __syncthreads();

    int wv = t >> 6, l = t & 63;
    int lrow = l & 15, lhi = l >> 4;

    short8 bfr[3][3];
    #pragma unroll
    for (int ntl = 0; ntl < 3; ++ntl) {
        int n = (wv*3 + ntl)*16 + lrow;
        #pragma unroll
        for (int kk = 0; kk < 3; ++kk)
            bfr[ntl][kk] = *reinterpret_cast<const short8*>(&Pl[n*BSTR + kk*32 + lhi*8]);
    }

    f32x4 acc[6][3];
    #pragma unroll
    for (int mt = 0; mt < 6; ++mt)
        #pragma unroll
        for (int ntl = 0; ntl < 3; ++ntl)
            acc[mt][ntl] = (f32x4){0.f,0.f,0.f,0.f};

    const unsigned short* Mc = Mg + c*9216;
    #pragma unroll
    for (int mt = 0; mt < 6; ++mt) {
        short8 afr[3];
        #pragma unroll
        for (int kk = 0; kk < 3; ++kk)
            afr[kk] = *reinterpret_cast<const short8*>(Mc + (mt*16 + lrow)*96 + kk*32 + lhi*8);
        #pragma unroll
        for (int ntl = 0; ntl < 3; ++ntl) {
            f32x4 d = acc[mt][ntl];
            #pragma unroll
            for (int kk = 0; kk < 3; ++kk)
                d = __builtin_amdgcn_mfma_f32_16x16x32_bf16(afr[kk], bfr[ntl][kk], d, 0, 0, 0);
            acc[mt][ntl] = d;
        }
    }
    __syncthreads();

    float* stage = reinterpret_cast<float*>(Pl);
    #pragma unroll
    for (int pass = 0; pass < 2; ++pass) {
        if ((wv >> 1) == pass) {
            #pragma unroll
            for (int mt = 0; mt < 6; ++mt)
                #pragma unroll
                for (int ntl = 0; ntl < 3; ++ntl) {
                    int n = (wv*3 + ntl)*16 + lrow - pass*96;
                    #pragma unroll
                    for (int r = 0; r < 4; ++r) {
                        int m = mt*16 + lhi*4 + r;
                        if (m <= 80) {
                            int i = m/9, j = m - 9*i;
                            stage[i*864 + n*9 + j] = acc[mt][ntl][r];
                        }
                    }
                }
        }
        __syncthreads();
        for (int idx = t; idx < 1944; idx += 256) {
            int i = idx/216, c4 = idx - i*216;
            float4 sv = *reinterpret_cast<const float4*>(&stage[i*864 + c4*4]);
            int ga = c*S1 + (ph*9 + i)*W1 + colbase + pass*864 + c4*4;
            float4 dv = *reinterpret_cast<const float4*>(&z[ga]);
            float4 ov;
            float cr;
            cr = sv.x*INV_NZ; ov.x = dv.x + (cr > 0.f ? cr : 0.2f*cr)*dv.x;
            cr = sv.y*INV_NZ; ov.y = dv.y + (cr > 0.f ? cr : 0.2f*cr)*dv.y;
            cr = sv.z*INV_NZ; ov.z = dv.z + (cr > 0.f ? cr : 0.2f*cr)*dv.z;
            cr = sv.w*INV_NZ; ov.w = dv.w + (cr > 0.f ? cr : 0.2f*cr)*dv.w;
            *reinterpret_cast<float4*>(&out[ga]) = ov;
        }
        __syncthreads();
    }
}

extern "C" void kernel_launch(void* const* d_in, const int* in_sizes, int n_in,
                              void* d_out, int out_size, void* d_ws, size_t ws_size,
                              hipStream_t stream)
{
    (void)in_sizes; (void)n_in; (void)out_size; (void)ws_size;
    const in_t* x     = (const in_t*)d_in[0];
    const in_t* y     = (const in_t*)d_in[1];
    const in_t* z     = (const in_t*)d_in[2];
    const in_t* w_img = (const in_t*)d_in[3];
    const in_t* b_img = (const in_t*)d_in[4];
    const in_t* w_fea = (const in_t*)d_in[5];
    const in_t* b_fea = (const in_t*)d_in[6];
    out_t* out = (out_t*)d_out;

    char* ws = (char*)d_ws;
    bf16*           xq = (bf16*)          (ws + 0);          // 23,887,872
    float*          yk = (float*)         (ws + 23887872);   // 5,971,968
    float*          xd = (float*)         (ws + 29859840);   // 5,971,968
    unsigned short* Mg = (unsigned short*)(ws + 35831808);   // 1,179,648

    hipLaunchKernelGGL(k_proj_x, dim3(1458), dim3(256), 0, stream, x, w_img, b_img, xq);
    hipLaunchKernelGGL(k_proj_y, dim3(1458), dim3(64),  0, stream, y, w_fea, b_fea, yk);
    hipLaunchKernelGGL(k_pool,   dim3(1152), dim3(256), 0, stream, z, xd);
    hipLaunchKernelGGL(k_M,      dim3(576),  dim3(256), 0, stream, xd, yk, Mg);
    hipLaunchKernelGGL(k_corr,   dim3(768),  dim3(256), 0, stream, Mg, xq, z, out);
}

// Round 11
// 84.993 us; speedup vs baseline: 1.2564x; 1.0659x over previous
//
#include <hip/hip_runtime.h>
#include <hip/hip_bf16.h>

typedef __hip_bfloat16 bf16;
typedef float in_t;
typedef float out_t;
typedef __attribute__((ext_vector_type(8))) short short8;   // 8 bf16 MFMA operand
typedef __attribute__((ext_vector_type(4))) float f32x4;    // MFMA accumulator

#define CH    64
#define CIN1  32
#define CIN2  64
#define S1    186624   // 36*72*72
#define W1    5184     // 72*72
#define S2    23328    // 18*36*36
#define W2    1296     // 36*36
#define LDSTR 1297     // k_M LDS row stride (coprime with 32)
#define BSTR  104      // k_corr patch lds bf16 row stride
#define XSTR  134      // proj_x LDS fp32 row stride
#define HWSTR 76       // pool LDS row stride
#define INV_NZ (1.0f/(288.0f + 1e-5f))

#define NB_PX 1458     // proj_x blocks
#define NB_PY 365      // proj_y blocks (4 wave-tiles each)
#define NB_PL 1152     // pool blocks

static __device__ __forceinline__ unsigned short f2bu(float f) {
    bf16 h = __float2bfloat16(f);
    unsigned short u;
    __builtin_memcpy(&u, &h, 2);
    return u;
}

// ---- fused stage 1: proj_x (MFMA) | proj_y (MFMA) | pool, disjoint block ranges
__global__ __launch_bounds__(256) void k_stage1(
    const in_t* __restrict__ x, const in_t* __restrict__ wi, const in_t* __restrict__ bi,
    bf16* __restrict__ xq,
    const in_t* __restrict__ y, const in_t* __restrict__ wf, const in_t* __restrict__ bf,
    float* __restrict__ yk,
    const in_t* __restrict__ z, float* __restrict__ xd)
{
    __shared__ __align__(16) char smem[22528];   // union arena: max(21248, 21888)
    int bid = blockIdx.x;
    int t   = threadIdx.x;

    if (bid < NB_PX) {
        // ---------- proj_x: xq(64,S1) = Wi(64,32) x x(32,S1) + bi, bf16 out ----------
        float*          xl = reinterpret_cast<float*>(smem);               // 32*XSTR
        unsigned short* wl = reinterpret_cast<unsigned short*>(smem + CIN1*XSTR*4);
        int gs0 = bid*128;
        #pragma unroll
        for (int i = 0; i < 4; ++i) {
            int fi = t + i*256;
            int c  = fi >> 5, s4 = fi & 31;
            float4 v = *reinterpret_cast<const float4*>(&x[(size_t)c*S1 + gs0 + s4*4]);
            float* dst = &xl[c*XSTR + s4*4];
            *reinterpret_cast<float2*>(dst)     = (float2){v.x, v.y};
            *reinterpret_cast<float2*>(dst + 2) = (float2){v.z, v.w};
        }
        #pragma unroll
        for (int i = 0; i < 2; ++i) {
            int wj = t + i*256;
            int o  = wj >> 3, c4 = wj & 7;
            float4 v = *reinterpret_cast<const float4*>(&wi[o*CIN1 + c4*4]);
            ushort4 u = { f2bu(v.x), f2bu(v.y), f2bu(v.z), f2bu(v.w) };
            *reinterpret_cast<ushort4*>(&wl[o*CIN1 + c4*4]) = u;
        }
        int l = t & 63, wv = t >> 6;
        int lcol = l & 15, loct = l >> 4;
        float bly[4];
        #pragma unroll
        for (int og = 0; og < 4; ++og) bly[og] = bi[og*16 + lcol];
        __syncthreads();

        short8 wfr[4];
        #pragma unroll
        for (int og = 0; og < 4; ++og)
            wfr[og] = *reinterpret_cast<const short8*>(&wl[(og*16 + lcol)*CIN1 + loct*8]);

        #pragma unroll
        for (int mt = 0; mt < 2; ++mt) {
            int s_base = (wv*2 + mt)*16;
            union { short8 v; unsigned short u[8]; } af;
            #pragma unroll
            for (int j = 0; j < 8; ++j)
                af.u[j] = f2bu(xl[(loct*8 + j)*XSTR + s_base + lcol]);
            #pragma unroll
            for (int og = 0; og < 4; ++og) {
                f32x4 d = { bly[og], bly[og], bly[og], bly[og] };
                d = __builtin_amdgcn_mfma_f32_16x16x32_bf16(af.v, wfr[og], d, 0, 0, 0);
                ushort4 r = { f2bu(d[0]), f2bu(d[1]), f2bu(d[2]), f2bu(d[3]) };
                int o = og*16 + lcol;
                *reinterpret_cast<ushort4*>(
                    (unsigned short*)xq + (size_t)o*S1 + gs0 + s_base + loct*4) = r;
            }
        }
    } else if (bid < NB_PX + NB_PY) {
        // ---------- proj_y: yk(64,S2) = Wf(64,64) x y(64,S2) + bf, fp32 out ----------
        int wv = t >> 6, l = t & 63;
        int tile = (bid - NB_PX)*4 + wv;          // 16-spatial tile
        if (tile < 1458) {
            int s0 = tile*16;
            int lcol = l & 15, loct = l >> 4;
            union { short8 v; unsigned short u[8]; } af[2];
            #pragma unroll
            for (int kk = 0; kk < 2; ++kk)
                #pragma unroll
                for (int j = 0; j < 8; ++j)
                    af[kk].u[j] = f2bu(y[(size_t)(kk*32 + loct*8 + j)*S2 + s0 + lcol]);
            #pragma unroll
            for (int og = 0; og < 4; ++og) {
                int o = og*16 + lcol;
                union { short8 v; unsigned short u[8]; } wfr[2];
                #pragma unroll
                for (int kk = 0; kk < 2; ++kk) {
                    float4 a  = *reinterpret_cast<const float4*>(&wf[o*CIN2 + kk*32 + loct*8]);
                    float4 bq = *reinterpret_cast<const float4*>(&wf[o*CIN2 + kk*32 + loct*8 + 4]);
                    wfr[kk].u[0]=f2bu(a.x);  wfr[kk].u[1]=f2bu(a.y);
                    wfr[kk].u[2]=f2bu(a.z);  wfr[kk].u[3]=f2bu(a.w);
                    wfr[kk].u[4]=f2bu(bq.x); wfr[kk].u[5]=f2bu(bq.y);
                    wfr[kk].u[6]=f2bu(bq.z); wfr[kk].u[7]=f2bu(bq.w);
                }
                float bo = bf[o];
                f32x4 d = { bo, bo, bo, bo };
                d = __builtin_amdgcn_mfma_f32_16x16x32_bf16(af[0].v, wfr[0].v, d, 0, 0, 0);
                d = __builtin_amdgcn_mfma_f32_16x16x32_bf16(af[1].v, wfr[1].v, d, 0, 0, 0);
                float4 r = { d[0], d[1], d[2], d[3] };
                *reinterpret_cast<float4*>(&yk[(size_t)o*S2 + s0 + loct*4]) = r;
            }
        }
    } else {
        // ---------- pool: AvgPool3d k3 s2 p1 cip=False, register d-sum + LDS hw ----------
        float* dsum = reinterpret_cast<float*>(smem);   // 72*HWSTR
        int pb = bid - NB_PX - NB_PY;
        int c = pb / 18, od = pb - (pb/18)*18;
        int dlo = od ? 2*od - 1 : 0;
        int nd  = od ? 3 : 2;
        const float4* zp = reinterpret_cast<const float4*>(z + ((size_t)c*36 + dlo)*W1);
        if (nd == 3) {
            for (int i = t; i < 1296; i += 256) {
                float4 a = zp[i], b = zp[1296 + i], e = zp[2592 + i];
                float4 s = { a.x+b.x+e.x, a.y+b.y+e.y, a.z+b.z+e.z, a.w+b.w+e.w };
                int r = i / 18, q = i - (i/18)*18;
                *reinterpret_cast<float4*>(&dsum[r*HWSTR + q*4]) = s;
            }
        } else {
            for (int i = t; i < 1296; i += 256) {
                float4 a = zp[i], b = zp[1296 + i];
                float4 s = { a.x+b.x, a.y+b.y, a.z+b.z, a.w+b.w };
                int r = i / 18, q = i - (i/18)*18;
                *reinterpret_cast<float4*>(&dsum[r*HWSTR + q*4]) = s;
            }
        }
        __syncthreads();
        float icd = (nd == 3) ? (1.f/3.f) : 0.5f;
        float* xdp = xd + (size_t)c*S2 + (size_t)od*W2;
        for (int idx = t; idx < 1296; idx += 256) {
            int oh = idx / 36, ow = idx - (idx/36)*36;
            int h0 = oh ? 2*oh-1 : 0, h1 = 2*oh+1;
            int w0 = ow ? 2*ow-1 : 0, w1 = 2*ow+1;
            float s = 0.f;
            for (int h = h0; h <= h1; ++h)
                for (int w = w0; w <= w1; ++w)
                    s += dsum[h*HWSTR + w];
            float ich = (h1 - h0) == 1 ? 0.5f : (1.f/3.f);
            float icw = (w1 - w0) == 1 ? 0.5f : (1.f/3.f);
            xdp[idx] = s * icd * ich * icw;
        }
    }
}

// ---- M[c,k1,k2] = sum_m Uxd[c,k1,m]*Uy[c,k2,m]; output bf16 zero-padded [c][96][96]
__global__ __launch_bounds__(256) void k_M(
    const float* __restrict__ xd, const float* __restrict__ yk, unsigned short* __restrict__ Mg)
{
    __shared__ float xl[3*LDSTR];
    __shared__ float yl[3*LDSTR];
    int b = blockIdx.x;
    int c = b / 9, r = b - c*9;
    int g = r / 3, h = r - g*3;
    int t = threadIdx.x;
    int t1 = t / 27, t2 = t - (t/27)*27;
    int offx[3];
    #pragma unroll
    for (int a = 0; a < 3; ++a) {
        int kl = t1*3 + a;
        offx[a] = (kl/9)*LDSTR + (kl - (kl/9)*9);
    }
    int offy = (t2/9)*LDSTR + (t2 - (t2/9)*9);
    float acc[3] = {};
    for (int ph2 = 0; ph2 < 2; ++ph2) {
        __syncthreads();
        for (int idx = t; idx < 3*W2; idx += 256) {
            int rr = idx / W2, col = idx - rr*W2;
            xl[rr*LDSTR + col] = xd[c*S2 + (ph2*9 + g*3 + rr)*W2 + col];
            yl[rr*LDSTR + col] = yk[c*S2 + (ph2*9 + h*3 + rr)*W2 + col];
        }
        __syncthreads();
        if (t < 243) {
            for (int m = 0; m < 144; ++m) {
                int cb = m*9;
                float yv = yl[cb + offy];
                #pragma unroll
                for (int a = 0; a < 3; ++a)
                    acc[a] += xl[cb + offx[a]] * yv;
            }
        }
    }
    if (t < 243) {
        #pragma unroll
        for (int a = 0; a < 3; ++a) {
            int k1 = g*27 + t1*3 + a;
            Mg[c*9216 + k1*96 + (h*27 + t2)] = f2bu(acc[a]);
        }
    }
    if (r == 0) {
        for (int idx = t; idx < 2655; idx += 256) {
            int row, col;
            if (idx < 1440) { int q = idx/96; row = 81 + q; col = idx - q*96; }
            else { int j = idx - 1440; int q = j/15; row = q; col = 81 + (j - q*15); }
            Mg[c*9216 + row*96 + col] = 0;
        }
    }
}

// ---- MFMA corr: per (channel, 192-patch chunk): C(96x192) = Mg(96x96,bf16) x Uxq^T
__global__ __launch_bounds__(256, 4) void k_corr(
    const unsigned short* __restrict__ Mg, const bf16* __restrict__ xq,
    const in_t* __restrict__ z, out_t* __restrict__ out)
{
    __shared__ __align__(16) unsigned short Pl[192*BSTR];   // 39936 B -> 4 blocks/CU
    int bid = blockIdx.x;
    int c   = bid / 12;
    int rem = bid - c*12;
    int ph  = rem / 3;
    int ck  = rem - ph*3;
    int colbase = ck*1728;
    int t = threadIdx.x;

    for (int idx = t; idx < 192*15; idx += 256) {
        int r = idx/15;
        Pl[r*BSTR + 81 + (idx - r*15)] = 0;
    }
    const unsigned short* xqu =
        (const unsigned short*)(xq + (size_t)c*S1 + (size_t)(ph*9)*W1 + colbase);
    for (int idx = t; idx < 3888; idx += 256) {
        int i2 = idx / 432, v4 = idx - i2*432;
        ushort4 vv = *reinterpret_cast<const ushort4*>(xqu + (size_t)i2*W1 + v4*4);
        int col = v4*4;
        unsigned short uu[4] = {vv.x, vv.y, vv.z, vv.w};
        #pragma unroll
        for (int j = 0; j < 4; ++j) {
            int cc = col + j;
            int p = cc/9, j2 = cc - p*9;
            Pl[p*BSTR + i2*9 + j2] = uu[j];
        }
    }
    __syncthreads();

    int wv = t >> 6, l = t & 63;
    int lrow = l & 15, lhi = l >> 4;

    short8 bfr[3][3];
    #pragma unroll
    for (int ntl = 0; ntl < 3; ++ntl) {
        int n = (wv*3 + ntl)*16 + lrow;
        #pragma unroll
        for (int kk = 0; kk < 3; ++kk)
            bfr[ntl][kk] = *reinterpret_cast<const short8*>(&Pl[n*BSTR + kk*32 + lhi*8]);
    }

    f32x4 acc[6][3];
    #pragma unroll
    for (int mt = 0; mt < 6; ++mt)
        #pragma unroll
        for (int ntl = 0; ntl < 3; ++ntl)
            acc[mt][ntl] = (f32x4){0.f,0.f,0.f,0.f};

    const unsigned short* Mc = Mg + c*9216;
    #pragma unroll
    for (int mt = 0; mt < 6; ++mt) {
        short8 afr[3];
        #pragma unroll
        for (int kk = 0; kk < 3; ++kk)
            afr[kk] = *reinterpret_cast<const short8*>(Mc + (mt*16 + lrow)*96 + kk*32 + lhi*8);
        #pragma unroll
        for (int ntl = 0; ntl < 3; ++ntl) {
            f32x4 d = acc[mt][ntl];
            #pragma unroll
            for (int kk = 0; kk < 3; ++kk)
                d = __builtin_amdgcn_mfma_f32_16x16x32_bf16(afr[kk], bfr[ntl][kk], d, 0, 0, 0);
            acc[mt][ntl] = d;
        }
    }
    __syncthreads();

    float* stage = reinterpret_cast<float*>(Pl);
    #pragma unroll
    for (int pass = 0; pass < 2; ++pass) {
        if ((wv >> 1) == pass) {
            #pragma unroll
            for (int mt = 0; mt < 6; ++mt)
                #pragma unroll
                for (int ntl = 0; ntl < 3; ++ntl) {
                    int n = (wv*3 + ntl)*16 + lrow - pass*96;
                    #pragma unroll
                    for (int r = 0; r < 4; ++r) {
                        int m = mt*16 + lhi*4 + r;
                        if (m <= 80) {
                            int i = m/9, j = m - 9*i;
                            stage[i*864 + n*9 + j] = acc[mt][ntl][r];
                        }
                    }
                }
        }
        __syncthreads();
        for (int idx = t; idx < 1944; idx += 256) {
            int i = idx/216, c4 = idx - i*216;
            float4 sv = *reinterpret_cast<const float4*>(&stage[i*864 + c4*4]);
            int ga = c*S1 + (ph*9 + i)*W1 + colbase + pass*864 + c4*4;
            float4 dv = *reinterpret_cast<const float4*>(&z[ga]);
            float4 ov;
            float cr;
            cr = sv.x*INV_NZ; ov.x = dv.x + (cr > 0.f ? cr : 0.2f*cr)*dv.x;
            cr = sv.y*INV_NZ; ov.y = dv.y + (cr > 0.f ? cr : 0.2f*cr)*dv.y;
            cr = sv.z*INV_NZ; ov.z = dv.z + (cr > 0.f ? cr : 0.2f*cr)*dv.z;
            cr = sv.w*INV_NZ; ov.w = dv.w + (cr > 0.f ? cr : 0.2f*cr)*dv.w;
            *reinterpret_cast<float4*>(&out[ga]) = ov;
        }
        __syncthreads();
    }
}

extern "C" void kernel_launch(void* const* d_in, const int* in_sizes, int n_in,
                              void* d_out, int out_size, void* d_ws, size_t ws_size,
                              hipStream_t stream)
{
    (void)in_sizes; (void)n_in; (void)out_size; (void)ws_size;
    const in_t* x     = (const in_t*)d_in[0];
    const in_t* y     = (const in_t*)d_in[1];
    const in_t* z     = (const in_t*)d_in[2];
    const in_t* w_img = (const in_t*)d_in[3];
    const in_t* b_img = (const in_t*)d_in[4];
    const in_t* w_fea = (const in_t*)d_in[5];
    const in_t* b_fea = (const in_t*)d_in[6];
    out_t* out = (out_t*)d_out;

    char* ws = (char*)d_ws;
    bf16*           xq = (bf16*)          (ws + 0);          // 23,887,872
    float*          yk = (float*)         (ws + 23887872);   // 5,971,968
    float*          xd = (float*)         (ws + 29859840);   // 5,971,968
    unsigned short* Mg = (unsigned short*)(ws + 35831808);   // 1,179,648

    hipLaunchKernelGGL(k_stage1, dim3(NB_PX + NB_PY + NB_PL), dim3(256), 0, stream,
                       x, w_img, b_img, xq, y, w_fea, b_fea, yk, z, xd);
    hipLaunchKernelGGL(k_M,      dim3(576), dim3(256), 0, stream, xd, yk, Mg);
    hipLaunchKernelGGL(k_corr,   dim3(768), dim3(256), 0, stream, Mg, xq, z, out);
}

// Round 12
// 82.077 us; speedup vs baseline: 1.3010x; 1.0355x over previous
//
#include <hip/hip_runtime.h>
#include <hip/hip_bf16.h>

typedef __hip_bfloat16 bf16;
typedef float in_t;
typedef float out_t;
typedef __attribute__((ext_vector_type(8))) short short8;   // 8 bf16 MFMA operand
typedef __attribute__((ext_vector_type(4))) float f32x4;    // MFMA accumulator

#define CH    64
#define CIN1  32
#define CIN2  64
#define S1    186624   // 36*72*72
#define W1    5184     // 72*72
#define S2    23328    // 18*36*36
#define W2    1296     // 36*36
#define LDSTR 1297     // k_M LDS row stride (coprime with 32)
#define BSTR  104      // k_corr patch lds bf16 row stride
#define XSTR  134      // proj_x input LDS fp32 row stride
#define OSTR  136      // proj_x output tile ushort stride (8-mult -> uint4 aligned)
#define YSTR  68       // proj_y output tile float stride
#define HWSTR 76       // pool LDS row stride
#define INV_NZ (1.0f/(288.0f + 1e-5f))

#define NB_PL 1152     // pool blocks (first: heaviest readers)
#define NB_PX 1458     // proj_x blocks
#define NB_PY 365      // proj_y blocks (4 wave-tiles each)

static __device__ __forceinline__ unsigned short f2bu(float f) {
    bf16 h = __float2bfloat16(f);
    unsigned short u;
    __builtin_memcpy(&u, &h, 2);
    return u;
}

// ---- fused stage 1: pool | proj_x (MFMA, LDS-restaged stores) | proj_y (MFMA, restaged)
__global__ __launch_bounds__(256) void k_stage1(
    const in_t* __restrict__ x, const in_t* __restrict__ wi, const in_t* __restrict__ bi,
    bf16* __restrict__ xq,
    const in_t* __restrict__ y, const in_t* __restrict__ wf, const in_t* __restrict__ bf,
    float* __restrict__ yk,
    const in_t* __restrict__ z, float* __restrict__ xd)
{
    __shared__ __align__(16) char smem[22528];
    int bid = blockIdx.x;
    int t   = threadIdx.x;

    if (bid < NB_PL) {
        // ---------- pool: AvgPool3d k3 s2 p1 cip=False, register d-sum + LDS hw ----------
        float* dsum = reinterpret_cast<float*>(smem);   // 72*HWSTR
        int c = bid / 18, od = bid - (bid/18)*18;
        int dlo = od ? 2*od - 1 : 0;
        int nd  = od ? 3 : 2;
        const float4* zp = reinterpret_cast<const float4*>(z + ((size_t)c*36 + dlo)*W1);
        if (nd == 3) {
            for (int i = t; i < 1296; i += 256) {
                float4 a = zp[i], b = zp[1296 + i], e = zp[2592 + i];
                float4 s = { a.x+b.x+e.x, a.y+b.y+e.y, a.z+b.z+e.z, a.w+b.w+e.w };
                int r = i / 18, q = i - (i/18)*18;
                *reinterpret_cast<float4*>(&dsum[r*HWSTR + q*4]) = s;
            }
        } else {
            for (int i = t; i < 1296; i += 256) {
                float4 a = zp[i], b = zp[1296 + i];
                float4 s = { a.x+b.x, a.y+b.y, a.z+b.z, a.w+b.w };
                int r = i / 18, q = i - (i/18)*18;
                *reinterpret_cast<float4*>(&dsum[r*HWSTR + q*4]) = s;
            }
        }
        __syncthreads();
        float icd = (nd == 3) ? (1.f/3.f) : 0.5f;
        float* xdp = xd + (size_t)c*S2 + (size_t)od*W2;
        for (int idx = t; idx < 1296; idx += 256) {
            int oh = idx / 36, ow = idx - (idx/36)*36;
            int h0 = oh ? 2*oh-1 : 0, h1 = 2*oh+1;
            int w0 = ow ? 2*ow-1 : 0, w1 = 2*ow+1;
            float s = 0.f;
            for (int h = h0; h <= h1; ++h)
                for (int w = w0; w <= w1; ++w)
                    s += dsum[h*HWSTR + w];
            float ich = (h1 - h0) == 1 ? 0.5f : (1.f/3.f);
            float icw = (w1 - w0) == 1 ? 0.5f : (1.f/3.f);
            xdp[idx] = s * icd * ich * icw;
        }
    } else if (bid < NB_PL + NB_PX) {
        // ---------- proj_x: xq(64,S1) = Wi(64,32) x x(32,S1) + bi, bf16 out ----------
        float*          xl = reinterpret_cast<float*>(smem);                   // 32*XSTR*4
        unsigned short* wl = reinterpret_cast<unsigned short*>(smem + CIN1*XSTR*4);
        int gs0 = (bid - NB_PL)*128;
        #pragma unroll
        for (int i = 0; i < 4; ++i) {
            int fi = t + i*256;
            int c  = fi >> 5, s4 = fi & 31;
            float4 v = *reinterpret_cast<const float4*>(&x[(size_t)c*S1 + gs0 + s4*4]);
            float* dst = &xl[c*XSTR + s4*4];
            *reinterpret_cast<float2*>(dst)     = (float2){v.x, v.y};
            *reinterpret_cast<float2*>(dst + 2) = (float2){v.z, v.w};
        }
        #pragma unroll
        for (int i = 0; i < 2; ++i) {
            int wj = t + i*256;
            int o  = wj >> 3, c4 = wj & 7;
            float4 v = *reinterpret_cast<const float4*>(&wi[o*CIN1 + c4*4]);
            ushort4 u = { f2bu(v.x), f2bu(v.y), f2bu(v.z), f2bu(v.w) };
            *reinterpret_cast<ushort4*>(&wl[o*CIN1 + c4*4]) = u;
        }
        int l = t & 63, wv = t >> 6;
        int lcol = l & 15, loct = l >> 4;
        float bly[4];
        #pragma unroll
        for (int og = 0; og < 4; ++og) bly[og] = bi[og*16 + lcol];
        __syncthreads();

        short8 wfr[4];
        #pragma unroll
        for (int og = 0; og < 4; ++og)
            wfr[og] = *reinterpret_cast<const short8*>(&wl[(og*16 + lcol)*CIN1 + loct*8]);

        ushort4 rr[2][4];
        #pragma unroll
        for (int mt = 0; mt < 2; ++mt) {
            int s_base = (wv*2 + mt)*16;
            union { short8 v; unsigned short u[8]; } af;
            #pragma unroll
            for (int j = 0; j < 8; ++j)
                af.u[j] = f2bu(xl[(loct*8 + j)*XSTR + s_base + lcol]);
            #pragma unroll
            for (int og = 0; og < 4; ++og) {
                f32x4 d = { bly[og], bly[og], bly[og], bly[og] };
                d = __builtin_amdgcn_mfma_f32_16x16x32_bf16(af.v, wfr[og], d, 0, 0, 0);
                rr[mt][og] = (ushort4){ f2bu(d[0]), f2bu(d[1]), f2bu(d[2]), f2bu(d[3]) };
            }
        }
        __syncthreads();   // xl/wl dead; reuse arena as output tile
        unsigned short* ot = reinterpret_cast<unsigned short*>(smem);  // 64 x OSTR
        #pragma unroll
        for (int mt = 0; mt < 2; ++mt)
            #pragma unroll
            for (int og = 0; og < 4; ++og)
                *reinterpret_cast<ushort4*>(
                    &ot[(og*16 + lcol)*OSTR + wv*32 + mt*16 + loct*4]) = rr[mt][og];
        __syncthreads();
        // coalesced copy: per instr 4 rows x 256B contiguous
        #pragma unroll
        for (int j = 0; j < 4; ++j) {
            int row = wv*16 + j*4 + (l >> 4);
            int c8  = l & 15;
            uint4 v = *reinterpret_cast<const uint4*>(&ot[row*OSTR + c8*8]);
            *reinterpret_cast<uint4*>(
                (unsigned short*)xq + (size_t)row*S1 + gs0 + c8*8) = v;
        }
    } else {
        // ---------- proj_y: yk(64,S2) = Wf(64,64) x y(64,S2) + bf, fp32 out ----------
        int pyb   = bid - NB_PL - NB_PX;
        int sblk0 = pyb*64;
        int wv = t >> 6, l = t & 63;
        int lcol = l & 15, loct = l >> 4;
        int tile = pyb*4 + wv;
        float* ot = reinterpret_cast<float*>(smem);     // 64 x YSTR floats
        bool act = (tile < 1458);
        f32x4 dv[4];
        if (act) {
            int s0 = tile*16;
            union { short8 v; unsigned short u[8]; } af[2];
            #pragma unroll
            for (int kk = 0; kk < 2; ++kk)
                #pragma unroll
                for (int j = 0; j < 8; ++j)
                    af[kk].u[j] = f2bu(y[(size_t)(kk*32 + loct*8 + j)*S2 + s0 + lcol]);
            #pragma unroll
            for (int og = 0; og < 4; ++og) {
                int o = og*16 + lcol;
                union { short8 v; unsigned short u[8]; } wfr[2];
                #pragma unroll
                for (int kk = 0; kk < 2; ++kk) {
                    float4 a  = *reinterpret_cast<const float4*>(&wf[o*CIN2 + kk*32 + loct*8]);
                    float4 bq = *reinterpret_cast<const float4*>(&wf[o*CIN2 + kk*32 + loct*8 + 4]);
                    wfr[kk].u[0]=f2bu(a.x);  wfr[kk].u[1]=f2bu(a.y);
                    wfr[kk].u[2]=f2bu(a.z);  wfr[kk].u[3]=f2bu(a.w);
                    wfr[kk].u[4]=f2bu(bq.x); wfr[kk].u[5]=f2bu(bq.y);
                    wfr[kk].u[6]=f2bu(bq.z); wfr[kk].u[7]=f2bu(bq.w);
                }
                float bo = bf[o];
                f32x4 d = { bo, bo, bo, bo };
                d = __builtin_amdgcn_mfma_f32_16x16x32_bf16(af[0].v, wfr[0].v, d, 0, 0, 0);
                d = __builtin_amdgcn_mfma_f32_16x16x32_bf16(af[1].v, wfr[1].v, d, 0, 0, 0);
                dv[og] = d;
            }
            #pragma unroll
            for (int og = 0; og < 4; ++og)
                *reinterpret_cast<float4*>(
                    &ot[(og*16 + lcol)*YSTR + wv*16 + loct*4]) =
                    (float4){ dv[og][0], dv[og][1], dv[og][2], dv[og][3] };
        }
        __syncthreads();
        #pragma unroll
        for (int j = 0; j < 4; ++j) {
            int row = wv*16 + j*4 + (l >> 4);
            int c4  = l & 15;
            int s   = sblk0 + c4*4;
            if (s < S2) {
                float4 v = *reinterpret_cast<const float4*>(&ot[row*YSTR + c4*4]);
                *reinterpret_cast<float4*>(&yk[(size_t)row*S2 + s]) = v;
            }
        }
    }
}

// ---- M[c,k1,k2] = sum_m Uxd[c,k1,m]*Uy[c,k2,m]; output bf16 zero-padded [c][96][96]
__global__ __launch_bounds__(256) void k_M(
    const float* __restrict__ xd, const float* __restrict__ yk, unsigned short* __restrict__ Mg)
{
    __shared__ float xl[3*LDSTR];
    __shared__ float yl[3*LDSTR];
    int b = blockIdx.x;
    int c = b / 9, r = b - c*9;
    int g = r / 3, h = r - g*3;
    int t = threadIdx.x;
    int t1 = t / 27, t2 = t - (t/27)*27;
    int offx[3];
    #pragma unroll
    for (int a = 0; a < 3; ++a) {
        int kl = t1*3 + a;
        offx[a] = (kl/9)*LDSTR + (kl - (kl/9)*9);
    }
    int offy = (t2/9)*LDSTR + (t2 - (t2/9)*9);
    float acc[3] = {};
    for (int ph2 = 0; ph2 < 2; ++ph2) {
        __syncthreads();
        for (int idx = t; idx < 3*W2; idx += 256) {
            int rr = idx / W2, col = idx - rr*W2;
            xl[rr*LDSTR + col] = xd[c*S2 + (ph2*9 + g*3 + rr)*W2 + col];
            yl[rr*LDSTR + col] = yk[c*S2 + (ph2*9 + h*3 + rr)*W2 + col];
        }
        __syncthreads();
        if (t < 243) {
            for (int m = 0; m < 144; ++m) {
                int cb = m*9;
                float yv = yl[cb + offy];
                #pragma unroll
                for (int a = 0; a < 3; ++a)
                    acc[a] += xl[cb + offx[a]] * yv;
            }
        }
    }
    if (t < 243) {
        #pragma unroll
        for (int a = 0; a < 3; ++a) {
            int k1 = g*27 + t1*3 + a;
            Mg[c*9216 + k1*96 + (h*27 + t2)] = f2bu(acc[a]);
        }
    }
    if (r == 0) {
        for (int idx = t; idx < 2655; idx += 256) {
            int row, col;
            if (idx < 1440) { int q = idx/96; row = 81 + q; col = idx - q*96; }
            else { int j = idx - 1440; int q = j/15; row = q; col = 81 + (j - q*15); }
            Mg[c*9216 + row*96 + col] = 0;
        }
    }
}

// ---- MFMA corr: per (channel, 192-patch chunk): C(96x192) = Mg(96x96,bf16) x Uxq^T
__global__ __launch_bounds__(256, 4) void k_corr(
    const unsigned short* __restrict__ Mg, const bf16* __restrict__ xq,
    const in_t* __restrict__ z, out_t* __restrict__ out)
{
    __shared__ __align__(16) unsigned short Pl[192*BSTR];   // 39936 B -> 4 blocks/CU
    int bid = blockIdx.x;
    int c   = bid / 12;
    int rem = bid - c*12;
    int ph  = rem / 3;
    int ck  = rem - ph*3;
    int colbase = ck*1728;
    int t = threadIdx.x;

    for (int idx = t; idx < 192*15; idx += 256) {
        int r = idx/15;
        Pl[r*BSTR + 81 + (idx - r*15)] = 0;
    }
    const unsigned short* xqu =
        (const unsigned short*)(xq + (size_t)c*S1 + (size_t)(ph*9)*W1 + colbase);
    for (int idx = t; idx < 3888; idx += 256) {
        int i2 = idx / 432, v4 = idx - i2*432;
        ushort4 vv = *reinterpret_cast<const ushort4*>(xqu + (size_t)i2*W1 + v4*4);
        int col = v4*4;
        unsigned short uu[4] = {vv.x, vv.y, vv.z, vv.w};
        #pragma unroll
        for (int j = 0; j < 4; ++j) {
            int cc = col + j;
            int p = cc/9, j2 = cc - p*9;
            Pl[p*BSTR + i2*9 + j2] = uu[j];
        }
    }
    __syncthreads();

    int wv = t >> 6, l = t & 63;
    int lrow = l & 15, lhi = l >> 4;

    short8 bfr[3][3];
    #pragma unroll
    for (int ntl = 0; ntl < 3; ++ntl) {
        int n = (wv*3 + ntl)*16 + lrow;
        #pragma unroll
        for (int kk = 0; kk < 3; ++kk)
            bfr[ntl][kk] = *reinterpret_cast<const short8*>(&Pl[n*BSTR + kk*32 + lhi*8]);
    }

    f32x4 acc[6][3];
    #pragma unroll
    for (int mt = 0; mt < 6; ++mt)
        #pragma unroll
        for (int ntl = 0; ntl < 3; ++ntl)
            acc[mt][ntl] = (f32x4){0.f,0.f,0.f,0.f};

    const unsigned short* Mc = Mg + c*9216;
    #pragma unroll
    for (int mt = 0; mt < 6; ++mt) {
        short8 afr[3];
        #pragma unroll
        for (int kk = 0; kk < 3; ++kk)
            afr[kk] = *reinterpret_cast<const short8*>(Mc + (mt*16 + lrow)*96 + kk*32 + lhi*8);
        #pragma unroll
        for (int ntl = 0; ntl < 3; ++ntl) {
            f32x4 d = acc[mt][ntl];
            #pragma unroll
            for (int kk = 0; kk < 3; ++kk)
                d = __builtin_amdgcn_mfma_f32_16x16x32_bf16(afr[kk], bfr[ntl][kk], d, 0, 0, 0);
            acc[mt][ntl] = d;
        }
    }
    __syncthreads();

    float* stage = reinterpret_cast<float*>(Pl);
    #pragma unroll
    for (int pass = 0; pass < 2; ++pass) {
        if ((wv >> 1) == pass) {
            #pragma unroll
            for (int mt = 0; mt < 6; ++mt)
                #pragma unroll
                for (int ntl = 0; ntl < 3; ++ntl) {
                    int n = (wv*3 + ntl)*16 + lrow - pass*96;
                    #pragma unroll
                    for (int r = 0; r < 4; ++r) {
                        int m = mt*16 + lhi*4 + r;
                        if (m <= 80) {
                            int i = m/9, j = m - 9*i;
                            stage[i*864 + n*9 + j] = acc[mt][ntl][r];
                        }
                    }
                }
        }
        __syncthreads();
        for (int idx = t; idx < 1944; idx += 256) {
            int i = idx/216, c4 = idx - i*216;
            float4 sv = *reinterpret_cast<const float4*>(&stage[i*864 + c4*4]);
            int ga = c*S1 + (ph*9 + i)*W1 + colbase + pass*864 + c4*4;
            float4 dv = *reinterpret_cast<const float4*>(&z[ga]);
            float4 ov;
            float cr;
            cr = sv.x*INV_NZ; ov.x = dv.x + (cr > 0.f ? cr : 0.2f*cr)*dv.x;
            cr = sv.y*INV_NZ; ov.y = dv.y + (cr > 0.f ? cr : 0.2f*cr)*dv.y;
            cr = sv.z*INV_NZ; ov.z = dv.z + (cr > 0.f ? cr : 0.2f*cr)*dv.z;
            cr = sv.w*INV_NZ; ov.w = dv.w + (cr > 0.f ? cr : 0.2f*cr)*dv.w;
            *reinterpret_cast<float4*>(&out[ga]) = ov;
        }
        __syncthreads();
    }
}

extern "C" void kernel_launch(void* const* d_in, const int* in_sizes, int n_in,
                              void* d_out, int out_size, void* d_ws, size_t ws_size,
                              hipStream_t stream)
{
    (void)in_sizes; (void)n_in; (void)out_size; (void)ws_size;
    const in_t* x     = (const in_t*)d_in[0];
    const in_t* y     = (const in_t*)d_in[1];
    const in_t* z     = (const in_t*)d_in[2];
    const in_t* w_img = (const in_t*)d_in[3];
    const in_t* b_img = (const in_t*)d_in[4];
    const in_t* w_fea = (const in_t*)d_in[5];
    const in_t* b_fea = (const in_t*)d_in[6];
    out_t* out = (out_t*)d_out;

    char* ws = (char*)d_ws;
    bf16*           xq = (bf16*)          (ws + 0);          // 23,887,872
    float*          yk = (float*)         (ws + 23887872);   // 5,971,968
    float*          xd = (float*)         (ws + 29859840);   // 5,971,968
    unsigned short* Mg = (unsigned short*)(ws + 35831808);   // 1,179,648

    hipLaunchKernelGGL(k_stage1, dim3(NB_PL + NB_PX + NB_PY), dim3(256), 0, stream,
                       x, w_img, b_img, xq, y, w_fea, b_fea, yk, z, xd);
    hipLaunchKernelGGL(k_M,      dim3(576), dim3(256), 0, stream, xd, yk, Mg);
    hipLaunchKernelGGL(k_corr,   dim3(768), dim3(256), 0, stream, Mg, xq, z, out);
}